// Round 8
// baseline (38.825 us; speedup 1.0000x reference)
//
#include <hip/hip_runtime.h>
#include <hip/hip_bf16.h>

// AdaGuidedFilter: x:(4,64,256,256) f32 -> out same shape.
// out = x * (A*x + (1-A)*mean), A = var/(var+eps),
// mean/var from 11x11 zero-padded box sums normalized by in-window count.
//
// R8: R6 structure (TILE_H=8, one barrier, short blocks) with 2 cols/thread:
// 128-thread blocks, float2 global loads, float4 (pair) LDS with pair-XOR
// swizzle, register-resident 6-pair window sliding 2 px per ds_read_b128.
// LDS instr/thread 33 b64 -> ~21 b128; load instrs halved.

#define RAD    5
#define KW     11
#define IMG_H  256
#define IMG_W  256
#define TILE_H 8
#define IN_H   (TILE_H + 2 * RAD)   // 18
#define STRIPS (IMG_H / TILE_H)     // 32
#define NPAIR  128                  // float2 column pairs per row
#define NBLK   (256 * STRIPS)       // 8192
#define EPS_F  0.01f

__device__ __forceinline__ float epil(float S, float S2, float inv, float xq) {
    const float mean = S * inv;
    const float m2   = S2 * inv;
    const float var  = fmaf(-mean, mean, m2);
    const float A    = var * __builtin_amdgcn_rcpf(var + EPS_F);
    return xq * fmaf(A, xq - mean, mean);
}

template<bool ROWCHECK>
__device__ __forceinline__ void run_strip(const float* __restrict__ xim,
                                          float* __restrict__ oim,
                                          float4* __restrict__ vs4,
                                          int strip, int t) {
    const int row0 = strip * TILE_H - RAD;

    // ---- phase 1: 2 columns per thread, vertical sliding sums ----
    {
        const int cc0 = t << 1;   // even column of this thread's pair
        float2 xr[IN_H];
        #pragma unroll
        for (int li = 0; li < IN_H; ++li) {
            const int g = row0 + li;   // block-uniform bound check
            if (!ROWCHECK || (g >= 0 && g < IMG_H))
                xr[li] = *reinterpret_cast<const float2*>(xim + (size_t)g * IMG_W + cc0);
            else
                xr[li] = make_float2(0.0f, 0.0f);
        }

        float s0 = 0.f, s20 = 0.f, s1 = 0.f, s21 = 0.f;
        #pragma unroll
        for (int li = 0; li < KW; ++li) {
            s0 += xr[li].x; s20 = fmaf(xr[li].x, xr[li].x, s20);
            s1 += xr[li].y; s21 = fmaf(xr[li].y, xr[li].y, s21);
        }
        #pragma unroll
        for (int r = 0; r < TILE_H; ++r) {
            vs4[(r << 7) | (t ^ r)] = make_float4(s0, s20, s1, s21);
            if (r < TILE_H - 1) {
                const float ax = xr[r + KW].x, bx = xr[r].x;
                const float ay = xr[r + KW].y, by = xr[r].y;
                s0 += ax - bx;  s20 = fmaf(ax, ax, fmaf(-bx, bx, s20));
                s1 += ay - by;  s21 = fmaf(ay, ay, fmaf(-by, by, s21));
            }
        }
    }
    __syncthreads();

    // ---- phase 2: 16 px per thread (one row, 8 pairs) ----
    const int lr  = t & 7;      // local row
    const int seg = t >> 3;     // 0..15, 16 columns each
    const int p0  = seg << 3;   // first output pair
    const int c0  = p0 << 1;    // first output column
    const int gr  = strip * TILE_H + lr;

    // epilogue x (L1/L2/L3-resident), issued before LDS window reads
    float xv[16];
    {
        const float4* xp = reinterpret_cast<const float4*>(xim + (size_t)gr * IMG_W + c0);
        #pragma unroll
        for (int j = 0; j < 4; ++j) {
            const float4 q = xp[j];
            xv[4*j+0] = q.x; xv[4*j+1] = q.y; xv[4*j+2] = q.z; xv[4*j+3] = q.w;
        }
    }

    const int rlo = (gr - RAD < 0) ? 0 : gr - RAD;
    const int rhi = (gr + RAD > IMG_H - 1) ? IMG_H - 1 : gr + RAD;
    const float rcnt = (float)(rhi - rlo + 1);

    float o[16];
    if (seg >= 1 && seg <= 14) {
        // interior: window pairs p0-3..p0+2 in registers, slide 2 px / 1 read
        float4 w0 = vs4[(lr << 7) | ((p0 - 3) ^ lr)];
        float4 w1 = vs4[(lr << 7) | ((p0 - 2) ^ lr)];
        float4 w2 = vs4[(lr << 7) | ((p0 - 1) ^ lr)];
        float4 w3 = vs4[(lr << 7) | ((p0    ) ^ lr)];
        float4 w4 = vs4[(lr << 7) | ((p0 + 1) ^ lr)];
        float4 w5 = vs4[(lr << 7) | ((p0 + 2) ^ lr)];
        float Fs  = (w1.x + w1.z) + (w2.x + w2.z) + (w3.x + w3.z) + (w4.x + w4.z) + (w5.x + w5.z);
        float Fs2 = (w1.y + w1.w) + (w2.y + w2.w) + (w3.y + w3.w) + (w4.y + w4.w) + (w5.y + w5.w);
        const float inv = __builtin_amdgcn_rcpf(rcnt * 11.0f);

        #pragma unroll
        for (int g = 0; g < 8; ++g) {
            const float Se  = Fs  + w0.z;          // even px: F + odd(p-3)
            const float Se2 = Fs2 + w0.w;
            const float4 nw = vs4[(lr << 7) | ((p0 + g + 3) ^ lr)];
            const float So  = Fs  + nw.x;          // odd px: F + even(p+3)
            const float So2 = Fs2 + nw.y;
            o[2*g]   = epil(Se, Se2, inv, xv[2*g]);
            o[2*g+1] = epil(So, So2, inv, xv[2*g+1]);
            Fs  += (nw.x + nw.z) - (w1.x + w1.z);
            Fs2 += (nw.y + nw.w) - (w1.y + w1.w);
            w0 = w1; w1 = w2; w2 = w3; w3 = w4; w4 = w5; w5 = nw;
        }
    } else {
        // edge segments (0, 15): bounds-checked float2 sliding window
        const float2* vs2 = reinterpret_cast<const float2*>(vs4);
        float s = 0.f, s2 = 0.f;
        #pragma unroll
        for (int dd = -RAD; dd <= RAD; ++dd) {
            const int cc = c0 + dd;
            if (cc >= 0 && cc < IMG_W) {
                const float2 v = vs2[((((lr << 7) | ((cc >> 1) ^ lr)) << 1) | (cc & 1))];
                s += v.x; s2 += v.y;
            }
        }
        #pragma unroll
        for (int i = 0; i < 16; ++i) {
            const int c   = c0 + i;
            const int wlo = (c - RAD < 0) ? 0 : c - RAD;
            const int whi = (c + RAD > IMG_W - 1) ? IMG_W - 1 : c + RAD;
            const float inv = __builtin_amdgcn_rcpf(rcnt * (float)(whi - wlo + 1));
            o[i] = epil(s, s2, inv, xv[i]);
            if (i < 15) {
                const int ca = c + RAD + 1;
                const int cs = c - RAD;
                if (ca < IMG_W) {
                    const float2 v = vs2[((((lr << 7) | ((ca >> 1) ^ lr)) << 1) | (ca & 1))];
                    s += v.x; s2 += v.y;
                }
                if (cs >= 0) {
                    const float2 v = vs2[((((lr << 7) | ((cs >> 1) ^ lr)) << 1) | (cs & 1))];
                    s -= v.x; s2 -= v.y;
                }
            }
        }
    }

    float4* orow = reinterpret_cast<float4*>(oim + (size_t)gr * IMG_W + c0);
    #pragma unroll
    for (int j = 0; j < 4; ++j)
        orow[j] = make_float4(o[4*j+0], o[4*j+1], o[4*j+2], o[4*j+3]);
}

__global__ __launch_bounds__(128)
void AdaGuidedFilter_17686675325295_kernel(const float* __restrict__ x,
                                           float* __restrict__ out) {
    __shared__ float4 vs4[TILE_H * NPAIR];   // 16384 B -> 10 blocks/CU (20 waves)

    // XCD-chunked swizzle (8192 % 8 == 0 -> bijective)
    const int d     = blockIdx.x;
    const int L     = (d & 7) * (NBLK / 8) + (d >> 3);
    const int img   = L >> 5;            // 0..255
    const int strip = L & (STRIPS - 1);  // 0..31
    const int t     = threadIdx.x;       // 0..127

    const float* __restrict__ xim = x   + (size_t)img * (IMG_H * IMG_W);
    float* __restrict__       oim = out + (size_t)img * (IMG_H * IMG_W);

    if (strip != 0 && strip != STRIPS - 1)
        run_strip<false>(xim, oim, vs4, strip, t);
    else
        run_strip<true>(xim, oim, vs4, strip, t);
}

extern "C" void kernel_launch(void* const* d_in, const int* in_sizes, int n_in,
                              void* d_out, int out_size, void* d_ws, size_t ws_size,
                              hipStream_t stream) {
    (void)in_sizes; (void)n_in; (void)d_ws; (void)ws_size; (void)out_size;
    const float* x = (const float*)d_in[0];
    float* out = (float*)d_out;
    dim3 grid(NBLK);     // 8192 blocks
    dim3 block(128);
    AdaGuidedFilter_17686675325295_kernel<<<grid, block, 0, stream>>>(x, out);
}